// Round 18
// baseline (1338.779 us; speedup 1.0000x reference)
//
#include <hip/hip_runtime.h>
#include <hip/hip_bf16.h>

#define NN 50000
#define NE 300000
#define DD 256
#define NCHUNK 293   // ceil(NE/1024)

typedef __hip_bfloat16 bf16;
typedef __attribute__((ext_vector_type(8))) short bf16x8;
typedef __attribute__((ext_vector_type(4))) float f32x4;

__device__ __forceinline__ float bf2f(bf16 v) { return __bfloat162float(v); }
__device__ __forceinline__ unsigned short f2b(float v) {
    bf16 t = __float2bfloat16(v);
    return *reinterpret_cast<unsigned short*>(&t);
}
__device__ __forceinline__ float b2f_bits(unsigned short u) {
    return __uint_as_float(((unsigned)u) << 16);
}
// tanh-form gelu: max err ~1e-3, branch-free
__device__ __forceinline__ float gelu_f(float v) {
    float v2 = v * v;
    float z  = v * fmaf(v2, 0.044715f, 1.0f) * 0.7978845608f;
    float e  = __expf(2.0f * z);
    float th = 1.0f - 2.0f / (e + 1.0f);
    return 0.5f * v * (1.0f + th);
}
// async global->LDS, 16B per lane; LDS dest = base + lane*16 (wave-linear)
__device__ __forceinline__ void gl2lds16(const uint4* g, uint4* l) {
    __builtin_amdgcn_global_load_lds(
        (const __attribute__((address_space(1))) void*)g,
        (__attribute__((address_space(3))) void*)l, 16, 0, 0);
}

// ---------------- edge partition by kg (stable, deterministic) ----------------
__global__ void part_count(const int* __restrict__ kg, int* __restrict__ bcnt) {
    int base = blockIdx.x * 1024;
    __shared__ int wc[4];
    int t = threadIdx.x, wave = t >> 6, lane = t & 63;
    int cnt = 0;
    #pragma unroll
    for (int s = 0; s < 4; ++s) {
        int j = base + s * 256 + t;
        int is0 = (j < NE && kg[j] == 0) ? 1 : 0;
        unsigned long long m = __ballot(is0);
        if (lane == 0) cnt += __popcll(m);
    }
    if (lane == 0) wc[wave] = cnt;
    __syncthreads();
    if (t == 0) bcnt[blockIdx.x] = wc[0] + wc[1] + wc[2] + wc[3];
}

// parallel exclusive scan of bcnt[0..n) (n <= 512), total -> meta[0]
__global__ __launch_bounds__(512) void part_scan(const int* __restrict__ bcnt,
                                                 int* __restrict__ bofs,
                                                 int* __restrict__ meta, int n) {
    __shared__ int tmp[512];
    int t = threadIdx.x;
    int v = (t < n) ? bcnt[t] : 0;
    tmp[t] = v;
    __syncthreads();
    #pragma unroll
    for (int off = 1; off < 512; off <<= 1) {
        int u = (t >= off) ? tmp[t - off] : 0;
        __syncthreads();
        tmp[t] += u;
        __syncthreads();
    }
    if (t < n) bofs[t] = tmp[t] - v;
    if (t == n - 1) meta[0] = tmp[t];
}

__global__ void part_scatter(const int* __restrict__ kg, const int* __restrict__ bofs,
                             const int* __restrict__ meta, int* __restrict__ perm) {
    int base = blockIdx.x * 1024;
    int c0 = meta[0];
    __shared__ int wz[4];
    int t = threadIdx.x, wave = t >> 6, lane = t & 63;
    int zrun = bofs[blockIdx.x];
    for (int s = 0; s < 4; ++s) {
        int j = base + s * 256 + t;
        int valid = j < NE;
        int is0 = (valid && kg[j] == 0) ? 1 : 0;
        unsigned long long m = __ballot(is0);
        int zb = __popcll(m & ((1ull << lane) - 1ull));
        if (lane == 0) wz[wave] = __popcll(m);
        __syncthreads();
        int wbefore = 0;
        for (int w = 0; w < wave; ++w) wbefore += wz[w];
        int zeros_before = zrun + wbefore + zb;
        if (valid) {
            int pos = is0 ? zeros_before : (c0 + (j - zeros_before));
            perm[pos] = j;
        }
        int stepz = wz[0] + wz[1] + wz[2] + wz[3];
        __syncthreads();
        zrun += stepz;
    }
}

// ---------------- CSR build (dst) ----------------
__global__ void deg_hist(const int* __restrict__ dst, int* __restrict__ deg) {
    int i = blockIdx.x * blockDim.x + threadIdx.x;
    if (i < NE) atomicAdd(&deg[dst[i]], 1);
}

// parallel exclusive scan over n entries; ofs[0..n] (ofs[n]=total); cur mirrors ofs
__global__ __launch_bounds__(1024) void scan_big(const int* __restrict__ in,
                                                 int* __restrict__ ofs,
                                                 int* __restrict__ cur, int n) {
    __shared__ int part[1024];
    int t = threadIdx.x;
    int C = (n + 1023) >> 10;
    int base = t * C;
    int s = 0;
    for (int j = 0; j < C; ++j) { int idx = base + j; if (idx < n) s += in[idx]; }
    part[t] = s;
    __syncthreads();
    #pragma unroll
    for (int off = 1; off < 1024; off <<= 1) {
        int u = (t >= off) ? part[t - off] : 0;
        __syncthreads();
        part[t] += u;
        __syncthreads();
    }
    int run = (t == 0) ? 0 : part[t - 1];
    for (int j = 0; j < C; ++j) {
        int idx = base + j;
        if (idx < n) {
            ofs[idx] = run;
            if (cur) cur[idx] = run;
            run += in[idx];
        }
    }
    if (t == 1023) ofs[n] = part[1023];
}

// each edge gets its CSR slot: ipos[e]
__global__ void csr_fill_ipos(const int* __restrict__ dst, int* __restrict__ cur,
                              int* __restrict__ ipos) {
    int i = blockIdx.x * blockDim.x + threadIdx.x;
    if (i < NE) {
        int p = atomicAdd(&cur[dst[i]], 1);
        ipos[i] = p;
    }
}

// flatten perm-indexed edge attributes into coalesced arrays
__global__ void build_perm_arrays(const int* __restrict__ perm,
        const int* __restrict__ src, const int* __restrict__ dst,
        const int* __restrict__ kgd, const int* __restrict__ ipos,
        int* __restrict__ src_p, int* __restrict__ dst_p,
        int* __restrict__ kgd_p, int* __restrict__ ipos_p) {
    int i = blockIdx.x * blockDim.x + threadIdx.x;
    if (i < NE) {
        int ge = perm[i];
        src_p[i] = src[ge];
        dst_p[i] = dst[ge];
        kgd_p[i] = kgd[ge];
        ipos_p[i] = ipos[ge];
    }
}

// ---------------- prep kernels ----------------
// relb stored in PERM order: relb[pos] = bf16(rel[perm[pos]])
__global__ __launch_bounds__(256) void f2b_perm_kernel(const float* __restrict__ rel,
        const int* __restrict__ perm, ushort* __restrict__ relb) {
    int row = blockIdx.x * 4 + (threadIdx.x >> 6);
    if (row >= NE) return;
    int lane = threadIdx.x & 63;
    int ge = perm[row];
    float4 f = ((const float4*)(rel + (size_t)ge * 256))[lane];
    ushort4 o;
    o.x = f2b(f.x); o.y = f2b(f.y); o.z = f2b(f.z); o.w = f2b(f.w);
    ((ushort4*)(relb + (size_t)row * 256))[lane] = o;
}

// out[s][o][d] = bf16(in[s][d][o]), dout = 256, din = 1<<shift
__global__ void transpose_w_kernel(const float* __restrict__ in, ushort* __restrict__ out,
                                   int shift, long total) {
    long i0 = (long)blockIdx.x * blockDim.x + threadIdx.x;
    long stride = (long)gridDim.x * blockDim.x;
    long dmask = ((long)1 << shift) - 1;
    for (long i = i0; i < total; i += stride) {
        long d = i & dmask;
        long rest = i >> shift;
        long o = rest & 255;
        long s = rest >> 8;
        out[i] = f2b(in[((s << shift) + d) * 256 + o]);
    }
}

__global__ void fill_kernel(float* __restrict__ p, float v, int n) {
    for (int i = blockIdx.x * blockDim.x + threadIdx.x; i < n; i += gridDim.x * blockDim.x)
        p[i] = v;
}

// ---------------- fused cast + layer-0 layernorm: h = x; hn = LN(x) ----------------
__global__ __launch_bounds__(256) void lnx_kernel(const float* __restrict__ x,
        const float* __restrict__ g, const float* __restrict__ b,
        float* __restrict__ h, bf16* __restrict__ hn) {
    int n = blockIdx.x * 4 + (threadIdx.x >> 6);
    if (n >= NN) return;
    int t = threadIdx.x & 63;
    float4 v = ((const float4*)(x + (size_t)n * DD))[t];
    ((float4*)(h + (size_t)n * DD))[t] = v;
    float s  = v.x + v.y + v.z + v.w;
    float s2 = v.x * v.x + v.y * v.y + v.z * v.z + v.w * v.w;
    #pragma unroll
    for (int off = 32; off; off >>= 1) {
        s  += __shfl_down(s, off);
        s2 += __shfl_down(s2, off);
    }
    s = __shfl(s, 0); s2 = __shfl(s2, 0);
    float mu  = s * (1.f / DD);
    float var = s2 * (1.f / DD) - mu * mu;
    float rs  = rsqrtf(var + 1e-5f);
    float vv[4] = {v.x, v.y, v.z, v.w};
    ushort4 pk;
    unsigned short* pku = (unsigned short*)&pk;
    #pragma unroll
    for (int j = 0; j < 4; ++j) {
        int c = t * 4 + j;
        pku[j] = f2b((vv[j] - mu) * rs * g[c] + b[c]);
    }
    ((ushort4*)(hn + (size_t)n * DD))[t] = pk;
}

// ---------------- node kernel: qn[br][node] = Wq[br]@hn + bq  AND
//                  hw[br][node] = Wt_upper[br]@hn + bt (both branches, shared staging)
__global__ __launch_bounds__(512) void nodeq_mfma(
        const bf16* __restrict__ hn,
        const ushort* __restrict__ WqT, const float* __restrict__ bq,
        const ushort* __restrict__ WtT, const float* __restrict__ bt,
        ushort* __restrict__ qn, ushort* __restrict__ hw) {
    __shared__ uint4 xh[64 * 32];   // 64 rows x 512B, xor-swizzled 16B slots
    __shared__ float bqs[2][256], bts[2][256];
    int t = threadIdx.x;
    int n0 = blockIdx.x * 64;
    int wave = t >> 6, lane = t & 63;
    if (t < 256) { bqs[0][t] = bq[t]; bqs[1][t] = bq[256 + t]; }
    else { int c = t & 255; bts[0][c] = bt[c]; bts[1][c] = bt[256 + c]; }
    const uint4* hn4 = (const uint4*)hn;
    #pragma unroll
    for (int j = 0; j < 4; ++j) {
        int pr = wave * 4 + j;
        int r2 = pr * 2 + (lane >> 5);
        int node = n0 + r2; if (node >= NN) node = NN - 1;
        int s = lane & 31;
        gl2lds16(hn4 + (size_t)node * 32 + (s ^ (r2 & 7)), &xh[pr * 64]);
    }
    __syncthreads();
    int lr = lane & 15, lg = lane >> 4;
    const char* xhb = (const char*)xh;
    f32x4 acc[2][2][4];
    // ---- phase A: hw = Wt_upper @ hn + bt (both branches) ----
    #pragma unroll
    for (int b = 0; b < 2; ++b)
        #pragma unroll
        for (int m = 0; m < 2; ++m)
            #pragma unroll
            for (int n = 0; n < 4; ++n) acc[b][m][n] = (f32x4){0.f, 0.f, 0.f, 0.f};
    {
        const ushort* tr0 = WtT + (size_t)(wave * 32 + lr) * 512 + lg * 8;
        const ushort* tr1 = WtT + (size_t)(wave * 32 + 16 + lr) * 512 + lg * 8;
        #pragma unroll
        for (int kk = 0; kk < 8; ++kk) {
            bf16x8 a00 = *(const bf16x8*)(tr0 + kk * 32);
            bf16x8 a01 = *(const bf16x8*)(tr1 + kk * 32);
            bf16x8 a10 = *(const bf16x8*)(tr0 + 131072 + kk * 32);
            bf16x8 a11 = *(const bf16x8*)(tr1 + 131072 + kk * 32);
            bf16x8 bfr[4];
            #pragma unroll
            for (int n = 0; n < 4; ++n) {
                int r = n * 16 + lr;
                bfr[n] = *(const bf16x8*)(xhb + r * 512 + (((kk * 4 + lg) ^ (r & 7)) << 4));
            }
            #pragma unroll
            for (int n = 0; n < 4; ++n) {
                acc[0][0][n] = __builtin_amdgcn_mfma_f32_16x16x32_bf16(a00, bfr[n], acc[0][0][n], 0, 0, 0);
                acc[0][1][n] = __builtin_amdgcn_mfma_f32_16x16x32_bf16(a01, bfr[n], acc[0][1][n], 0, 0, 0);
                acc[1][0][n] = __builtin_amdgcn_mfma_f32_16x16x32_bf16(a10, bfr[n], acc[1][0][n], 0, 0, 0);
                acc[1][1][n] = __builtin_amdgcn_mfma_f32_16x16x32_bf16(a11, bfr[n], acc[1][1][n], 0, 0, 0);
            }
        }
    }
    #pragma unroll
    for (int n = 0; n < 4; ++n) {
        int e = n * 16 + lr;
        int node = n0 + e;
        if (node < NN) {
            #pragma unroll
            for (int br = 0; br < 2; ++br)
                #pragma unroll
                for (int m = 0; m < 2; ++m) {
                    int ob = wave * 32 + m * 16 + lg * 4;
                    f32x4 a = acc[br][m][n];
                    ushort4 pk;
                    unsigned short* pu = (unsigned short*)&pk;
                    #pragma unroll
                    for (int r = 0; r < 4; ++r) pu[r] = f2b(a[r] + bts[br][ob + r]);
                    *(ushort4*)(hw + ((size_t)br * NN + node) * 256 + ob) = pk;
                }
        }
    }
    // ---- phase B: qn = Wq @ hn + bq (both branches), reuse acc ----
    #pragma unroll
    for (int b = 0; b < 2; ++b)
        #pragma unroll
        for (int m = 0; m < 2; ++m)
            #pragma unroll
            for (int n = 0; n < 4; ++n) acc[b][m][n] = (f32x4){0.f, 0.f, 0.f, 0.f};
    {
        const ushort* qr0 = WqT + (size_t)(wave * 32 + lr) * 256 + lg * 8;
        const ushort* qr1 = WqT + (size_t)(wave * 32 + 16 + lr) * 256 + lg * 8;
        #pragma unroll
        for (int kk = 0; kk < 8; ++kk) {
            bf16x8 a00 = *(const bf16x8*)(qr0 + kk * 32);
            bf16x8 a01 = *(const bf16x8*)(qr1 + kk * 32);
            bf16x8 a10 = *(const bf16x8*)(qr0 + 65536 + kk * 32);
            bf16x8 a11 = *(const bf16x8*)(qr1 + 65536 + kk * 32);
            bf16x8 bfr[4];
            #pragma unroll
            for (int n = 0; n < 4; ++n) {
                int r = n * 16 + lr;
                bfr[n] = *(const bf16x8*)(xhb + r * 512 + (((kk * 4 + lg) ^ (r & 7)) << 4));
            }
            #pragma unroll
            for (int n = 0; n < 4; ++n) {
                acc[0][0][n] = __builtin_amdgcn_mfma_f32_16x16x32_bf16(a00, bfr[n], acc[0][0][n], 0, 0, 0);
                acc[0][1][n] = __builtin_amdgcn_mfma_f32_16x16x32_bf16(a01, bfr[n], acc[0][1][n], 0, 0, 0);
                acc[1][0][n] = __builtin_amdgcn_mfma_f32_16x16x32_bf16(a10, bfr[n], acc[1][0][n], 0, 0, 0);
                acc[1][1][n] = __builtin_amdgcn_mfma_f32_16x16x32_bf16(a11, bfr[n], acc[1][1][n], 0, 0, 0);
            }
        }
    }
    #pragma unroll
    for (int n = 0; n < 4; ++n) {
        int e = n * 16 + lr;
        int node = n0 + e;
        if (node < NN) {
            #pragma unroll
            for (int br = 0; br < 2; ++br)
                #pragma unroll
                for (int m = 0; m < 2; ++m) {
                    int ob = wave * 32 + m * 16 + lg * 4;
                    f32x4 a = acc[br][m][n];
                    ushort4 pk;
                    unsigned short* pu = (unsigned short*)&pk;
                    #pragma unroll
                    for (int r = 0; r < 4; ++r) pu[r] = f2b(a[r] + bqs[br][ob + r]);
                    *(ushort4*)(qn + ((size_t)br * NN + node) * 256 + ob) = pk;
                }
        }
    }
}

// ---------------- transfer (+fused k +fused att): 32-edge kg_src-homogeneous tiles ----------------
// identical structure to the 64-edge version; tile halved to cut regs/LDS -> 3 blocks/CU
template<int RELB>
__global__ __launch_bounds__(512, 4) void transfer_mfma(
        const float* __restrict__ rel, const ushort* __restrict__ relb,
        const int* __restrict__ perm,
        const int* __restrict__ src_p, const int* __restrict__ dst_p,
        const int* __restrict__ kgd_p, const int* __restrict__ ipos_p,
        const int* __restrict__ meta,
        const ushort* __restrict__ WtT,
        const ushort* __restrict__ WkT, const float* __restrict__ bk,
        const ushort* __restrict__ qn, const ushort* __restrict__ hw,
        const float* __restrict__ beta_p,
        bf16* __restrict__ xjt, float* __restrict__ att) {
    __shared__ uint4 xr[32 * 32];   // 16 KB: rel tile -> xjt tile
    __shared__ float bks[256];
    __shared__ float patt[8][32];
    __shared__ int ssrc[32], sdst[32], sgd[32], sip[32], sval[32];
    int t = threadIdx.x;
    int c0 = meta[0];
    int tiles0 = (c0 + 31) >> 5;
    int tiles1 = (NE - c0 + 31) >> 5;
    int bid = blockIdx.x;
    if (bid >= tiles0 + tiles1) return;
    int kgt, start, end;
    if (bid < tiles0) { kgt = 0; start = bid * 32; end = c0; }
    else              { kgt = 1; start = c0 + (bid - tiles0) * 32; end = NE; }
    int wave = t >> 6, lane = t & 63;
    if (t < 32) {
        int pos = start + t;
        int v = pos < end;
        int cp = v ? pos : end - 1;
        sval[t] = v;
        ssrc[t] = src_p[cp];
        sdst[t] = dst_p[cp];
        sgd[t]  = kgd_p[cp];
        sip[t]  = ipos_p[cp];
    } else if (t >= 256) {
        bks[t - 256] = bk[kgt * 256 + (t - 256)];
    }
    __syncthreads();
    // ---- stage rel tile (32 rows x 512B); perm-ordered -> address is arithmetic ----
    if (RELB) {
        const uint4* rb4 = (const uint4*)relb;
        #pragma unroll
        for (int j = 0; j < 2; ++j) {
            int pr = wave * 2 + j;
            int r2 = pr * 2 + (lane >> 5);
            int rp = start + r2; if (rp >= end) rp = end - 1;
            int s = lane & 31;
            gl2lds16(rb4 + (size_t)rp * 32 + (s ^ (r2 & 7)), &xr[pr * 64]);
        }
    } else {
        #pragma unroll
        for (int i = 0; i < 4; ++i) {
            int r = i * 8 + wave;
            int rp = start + r; if (rp >= end) rp = end - 1;
            int ge = perm[rp];
            float4 f = ((const float4*)(rel + (size_t)ge * 256))[lane];
            ushort4 o;
            o.x = f2b(f.x); o.y = f2b(f.y); o.z = f2b(f.z); o.w = f2b(f.w);
            int s = lane >> 1;
            char* bp = (char*)&xr[r * 32] + (((s ^ (r & 7)) << 4) | ((lane & 1) << 3));
            *(ushort4*)bp = o;
        }
    }
    int lr = lane & 15, lg = lane >> 4;
    // ---- gathers: hw (consumed immediately into acc) + qn (held for att) ----
    f32x4 acc[2][2];
    #pragma unroll
    for (int n = 0; n < 2; ++n) {
        int e = n * 16 + lr;
        size_t hb = ((size_t)kgt * NN + ssrc[e]) * 256;
        #pragma unroll
        for (int m = 0; m < 2; ++m) {
            int ob = wave * 32 + m * 16 + lg * 4;
            ushort4 w4 = *(const ushort4*)(hw + hb + ob);
            acc[m][n] = (f32x4){b2f_bits(w4.x), b2f_bits(w4.y), b2f_bits(w4.z), b2f_bits(w4.w)};
        }
    }
    ushort4 kv[2][2];
    #pragma unroll
    for (int n = 0; n < 2; ++n) {
        int e = n * 16 + lr;
        size_t qb = ((size_t)sgd[e] * NN + sdst[e]) * 256;
        #pragma unroll
        for (int m = 0; m < 2; ++m) {
            int ob = wave * 32 + m * 16 + lg * 4;
            kv[m][n] = *(const ushort4*)(qn + qb + ob);
        }
    }
    __syncthreads();
    // ---- 8 kk MFMA on rel with Wt_lower (acc pre-initialized from hw) ----
    const char* xrb = (const char*)xr;
    const ushort* wb = WtT + (size_t)kgt * 131072;
    const ushort* wrow0 = wb + (size_t)(wave * 32 + lr) * 512 + 256 + lg * 8;       // lower half
    const ushort* wrow1 = wb + (size_t)(wave * 32 + 16 + lr) * 512 + 256 + lg * 8;
    __builtin_amdgcn_s_setprio(1);
    #pragma unroll
    for (int kk = 0; kk < 8; ++kk) {
        bf16x8 a0 = *(const bf16x8*)(wrow0 + kk * 32);
        bf16x8 a1 = *(const bf16x8*)(wrow1 + kk * 32);
        bf16x8 bfr[2];
        #pragma unroll
        for (int n = 0; n < 2; ++n) {
            int r = n * 16 + lr;
            bfr[n] = *(const bf16x8*)(xrb + r * 512 + (((kk * 4 + lg) ^ (r & 7)) << 4));
        }
        #pragma unroll
        for (int m = 0; m < 2; ++m)
            #pragma unroll
            for (int n = 0; n < 2; ++n)
                acc[m][n] = __builtin_amdgcn_mfma_f32_16x16x32_bf16((m ? a1 : a0), bfr[n], acc[m][n], 0, 0, 0);
    }
    __builtin_amdgcn_s_setprio(0);
    __syncthreads();
    // ---- epilogue: gelu (bias already in hw), pack bf16 into swizzled 512B rows ----
    char* xob = (char*)xr;
    #pragma unroll
    for (int n = 0; n < 2; ++n) {
        int e = n * 16 + lr;
        #pragma unroll
        for (int m = 0; m < 2; ++m) {
            int ob = wave * 32 + m * 16 + lg * 4;
            f32x4 a = acc[m][n];
            ushort4 pk;
            unsigned short* pu = (unsigned short*)&pk;
            #pragma unroll
            for (int r = 0; r < 4; ++r)
                pu[r] = f2b(gelu_f(a[r]));
            int bofs = ob * 2;
            int slot = ((bofs >> 4) ^ (e & 7));
            *(ushort4*)(xob + e * 512 + slot * 16 + (bofs & 15)) = pk;
        }
    }
    __syncthreads();
    // ---- xjt global store to CSR slots (drains under the k-pass MFMA) ----
    uint4* xjv = (uint4*)xjt;
    #pragma unroll
    for (int i = 0; i < 2; ++i) {
        int flat = i * 512 + t;
        int r = flat >> 5, c = flat & 31;
        if (sval[r])
            xjv[(size_t)sip[r] * 32 + c] = *(const uint4*)(xob + r * 512 + ((c ^ (r & 7)) << 4));
    }
    // ---- fused k-pass: k = Wk[kg] @ xjt_tile (reuses acc) ----
    #pragma unroll
    for (int m = 0; m < 2; ++m)
        #pragma unroll
        for (int n = 0; n < 2; ++n) acc[m][n] = (f32x4){0.f, 0.f, 0.f, 0.f};
    const ushort* kbw = WkT + (size_t)kgt * 65536;
    const ushort* kr0 = kbw + (size_t)(wave * 32 + lr) * 256 + lg * 8;
    const ushort* kr1 = kbw + (size_t)(wave * 32 + 16 + lr) * 256 + lg * 8;
    __builtin_amdgcn_s_setprio(1);
    #pragma unroll
    for (int kk = 0; kk < 8; ++kk) {
        bf16x8 a0 = *(const bf16x8*)(kr0 + kk * 32);
        bf16x8 a1 = *(const bf16x8*)(kr1 + kk * 32);
        bf16x8 bfr[2];
        #pragma unroll
        for (int n = 0; n < 2; ++n) {
            int r = n * 16 + lr;
            bfr[n] = *(const bf16x8*)(xob + r * 512 + (((kk * 4 + lg) ^ (r & 7)) << 4));
        }
        #pragma unroll
        for (int n = 0; n < 2; ++n) {
            acc[0][n] = __builtin_amdgcn_mfma_f32_16x16x32_bf16(a0, bfr[n], acc[0][n], 0, 0, 0);
            acc[1][n] = __builtin_amdgcn_mfma_f32_16x16x32_bf16(a1, bfr[n], acc[1][n], 0, 0, 0);
        }
    }
    __builtin_amdgcn_s_setprio(0);
    // ---- fused att: lane-local q.k dot with pre-gathered kv, reduce over lg ----
    float p[2];
    #pragma unroll
    for (int n = 0; n < 2; ++n) {
        float s = 0.f;
        #pragma unroll
        for (int m = 0; m < 2; ++m) {
            int ob = wave * 32 + m * 16 + lg * 4;
            ushort4 qv = kv[m][n];
            f32x4 kcv = acc[m][n];
            s = fmaf(b2f_bits(qv.x), kcv[0] + bks[ob + 0], s);
            s = fmaf(b2f_bits(qv.y), kcv[1] + bks[ob + 1], s);
            s = fmaf(b2f_bits(qv.z), kcv[2] + bks[ob + 2], s);
            s = fmaf(b2f_bits(qv.w), kcv[3] + bks[ob + 3], s);
        }
        p[n] = s;
    }
    #pragma unroll
    for (int n = 0; n < 2; ++n) {
        p[n] += __shfl_xor(p[n], 16);
        p[n] += __shfl_xor(p[n], 32);
    }
    if (lane < 16) {
        #pragma unroll
        for (int n = 0; n < 2; ++n) patt[wave][n * 16 + lr] = p[n];
    }
    __syncthreads();
    if (t < 128) {
        int e = t & 31, h = t >> 5;
        if (sval[e]) {
            int pos = start + e;
            float bv = beta_p[pos];
            att[(size_t)sip[e] * 4 + h] = (patt[2 * h][e] + patt[2 * h + 1][e]) * bv * 0.125f;
        }
    }
}

// ---------------- fused softmax + aggregate + residual + gelu (+ next-layer LN) ----------------
// att/xjt are in CSR-slot order -> fully sequential reads, no eid indirection
template<int WRITE_HN>
__global__ __launch_bounds__(256) void aggregate_kernel(
        const float* __restrict__ att, const bf16* __restrict__ xjt,
        const int* __restrict__ ofs,
        float* __restrict__ h, const float* __restrict__ g, const float* __restrict__ b,
        bf16* __restrict__ hn) {
    int node = blockIdx.x * 4 + (threadIdx.x >> 6);
    if (node >= NN) return;
    int lane = threadIdx.x & 63;
    int hh = lane >> 4;
    int beg = ofs[node], end = ofs[node + 1];
    float m = -1e30f, den = 0.f;
    float a0 = 0.f, a1 = 0.f, a2 = 0.f, a3 = 0.f;
    for (int i = beg; i < end; ++i) {
        float av = att[(size_t)i * 4 + hh];
        if (av > m) {
            float r = __expf(m - av);
            den *= r; a0 *= r; a1 *= r; a2 *= r; a3 *= r;
            m = av;
        }
        float wgt = __expf(av - m);
        den += wgt;
        ushort4 v = *(const ushort4*)((const ushort*)xjt + (size_t)i * 256 + lane * 4);
        a0 = fmaf(wgt, b2f_bits(v.x), a0);
        a1 = fmaf(wgt, b2f_bits(v.y), a1);
        a2 = fmaf(wgt, b2f_bits(v.z), a2);
        a3 = fmaf(wgt, b2f_bits(v.w), a3);
    }
    float inv = 1.f / (den + 1e-16f);
    float4 hv = ((float4*)(h + (size_t)node * 256))[lane];
    hv.x += gelu_f(a0 * inv);
    hv.y += gelu_f(a1 * inv);
    hv.z += gelu_f(a2 * inv);
    hv.w += gelu_f(a3 * inv);
    ((float4*)(h + (size_t)node * 256))[lane] = hv;
    if (WRITE_HN) {
        float s  = hv.x + hv.y + hv.z + hv.w;
        float s2 = hv.x * hv.x + hv.y * hv.y + hv.z * hv.z + hv.w * hv.w;
        #pragma unroll
        for (int off = 32; off; off >>= 1) {
            s  += __shfl_down(s, off);
            s2 += __shfl_down(s2, off);
        }
        s = __shfl(s, 0); s2 = __shfl(s2, 0);
        float mu  = s * (1.f / DD);
        float var = s2 * (1.f / DD) - mu * mu;
        float rs  = rsqrtf(var + 1e-5f);
        float vv[4] = {hv.x, hv.y, hv.z, hv.w};
        ushort4 pk;
        unsigned short* pku = (unsigned short*)&pk;
        #pragma unroll
        for (int j = 0; j < 4; ++j) {
            int c = lane * 4 + j;
            pku[j] = f2b((vv[j] - mu) * rs * g[c] + b[c]);
        }
        ((ushort4*)(hn + (size_t)node * DD))[lane] = pk;
    }
}

// beta in perm order (coalesced read in transfer's att write)
__global__ void beta_perm_kernel(const float* __restrict__ beta, const int* __restrict__ perm,
                                 float* __restrict__ beta_p) {
    int i = blockIdx.x * blockDim.x + threadIdx.x;
    if (i < NE) beta_p[i] = beta[perm[i]];
}

extern "C" void kernel_launch(void* const* d_in, const int* in_sizes, int n_in,
                              void* d_out, int out_size, void* d_ws, size_t ws_size,
                              hipStream_t stream) {
    const float* x    = (const float*)d_in[0];
    const int*   ei   = (const int*)d_in[1];
    const int*   ekg  = (const int*)d_in[2];
    const float* beta = (const float*)d_in[3];
    const float* rel  = (const float*)d_in[4];
    const float* ln_g = (const float*)d_in[5];
    const float* ln_b = (const float*)d_in[6];
    const float* Wt   = (const float*)d_in[7];
    const float* bt   = (const float*)d_in[8];
    const float* Wq   = (const float*)d_in[9];
    const float* bq   = (const float*)d_in[10];
    const float* Wk   = (const float*)d_in[11];
    const float* bk   = (const float*)d_in[12];

    float* h = (float*)d_out;   // residual stream (f32) in d_out

    const int* srcp = ei;
    const int* dstp = ei + NE;
    const int* kgs  = ekg;
    const int* kgd  = ekg + NE;

    char* w = (char*)d_ws;
    float*  att   = (float*)w;  w += (size_t)NE * 4 * 4;         //  4.8 MB
    bf16*   hn    = (bf16*)w;   w += (size_t)NN * DD * 2;        // 25.6 MB
    bf16*   xjt   = (bf16*)w;   w += (size_t)NE * DD * 2;        // 153.6 MB
    ushort* qn    = (ushort*)w; w += (size_t)2 * NN * DD * 2;    // 51.2 MB
    ushort* hw    = (ushort*)w; w += (size_t)2 * NN * DD * 2;    // 51.2 MB
    ushort* WtT   = (ushort*)w; w += (size_t)4 * 256 * 512 * 2;  // 1 MB
    ushort* WqT   = (ushort*)w; w += (size_t)4 * 256 * 256 * 2;
    ushort* WkT   = (ushort*)w; w += (size_t)4 * 256 * 256 * 2;
    int* perm_src = (int*)w;    w += (size_t)NE * 4;             // 1.2 MB
    int* bcnt0    = (int*)w;    w += NCHUNK * 4;
    int* bofs0    = (int*)w;    w += NCHUNK * 4;
    int* meta0    = (int*)w;    w += 64;
    int* deg      = (int*)w;    w += (size_t)NN * 4;
    int* ofs      = (int*)w;    w += (size_t)(NN + 1) * 4;
    int* cur      = (int*)w;    w += (size_t)NN * 4;
    int* ipos     = (int*)w;    w += (size_t)NE * 4;             // 1.2 MB
    int* src_p    = (int*)w;    w += (size_t)NE * 4;
    int* dst_p    = (int*)w;    w += (size_t)NE * 4;
    int* kgd_p    = (int*)w;    w += (size_t)NE * 4;
    int* ipos_p   = (int*)w;    w += (size_t)NE * 4;
    float* beta_p = (float*)w;  w += (size_t)NE * 4;
    size_t used = (size_t)(w - (char*)d_ws);
    ushort* relb = (ushort*)w;
    int use_relb = (ws_size >= used + (size_t)NE * DD * 2) ? 1 : 0;

    // edge partition by kg_src (stable, static across layers)
    part_count<<<NCHUNK, 256, 0, stream>>>(kgs, bcnt0);
    part_scan<<<1, 512, 0, stream>>>(bcnt0, bofs0, meta0, NCHUNK);
    part_scatter<<<NCHUNK, 256, 0, stream>>>(kgs, bofs0, meta0, perm_src);

    // CSR slots by dst
    fill_kernel<<<64, 256, 0, stream>>>((float*)deg, 0.f, NN);
    deg_hist<<<(NE + 255) / 256, 256, 0, stream>>>(dstp, deg);
    scan_big<<<1, 1024, 0, stream>>>(deg, ofs, cur, NN);
    csr_fill_ipos<<<(NE + 255) / 256, 256, 0, stream>>>(dstp, cur, ipos);

    // perm-flattened edge attribute arrays
    build_perm_arrays<<<(NE + 255) / 256, 256, 0, stream>>>(perm_src, srcp, dstp, kgd, ipos,
            src_p, dst_p, kgd_p, ipos_p);
    beta_perm_kernel<<<(NE + 255) / 256, 256, 0, stream>>>(beta, perm_src, beta_p);

    if (use_relb)
        f2b_perm_kernel<<<(NE + 3) / 4, 256, 0, stream>>>(rel, perm_src, relb);
    transpose_w_kernel<<<512, 256, 0, stream>>>(Wt, WtT, 9, (long)4 * 256 * 512);
    transpose_w_kernel<<<256, 256, 0, stream>>>(Wq, WqT, 8, (long)4 * 256 * 256);
    transpose_w_kernel<<<256, 256, 0, stream>>>(Wk, WkT, 8, (long)4 * 256 * 256);

    const int EBP = NE / 32 + 2;       // 9377 tiles (both kg halves)
    const int QB  = (NN + 63) / 64;
    const int AGB = (NN + 3) / 4;

    // layer 0: fused cast + LN
    lnx_kernel<<<AGB, 256, 0, stream>>>(x, ln_g, ln_b, h, hn);
    for (int l = 0; l < 2; ++l) {
        nodeq_mfma<<<QB, 512, 0, stream>>>(hn,
                WqT + (size_t)l * 2 * 256 * 256, bq + l * 512,
                WtT + (size_t)l * 2 * 256 * 512, bt + l * 512, qn, hw);
        if (use_relb)
            transfer_mfma<1><<<EBP, 512, 0, stream>>>(rel, relb, perm_src,
                    src_p, dst_p, kgd_p, ipos_p, meta0,
                    WtT + (size_t)l * 2 * 256 * 512,
                    WkT + (size_t)l * 2 * 256 * 256, bk + l * 512, qn, hw, beta_p, xjt, att);
        else
            transfer_mfma<0><<<EBP, 512, 0, stream>>>(rel, relb, perm_src,
                    src_p, dst_p, kgd_p, ipos_p, meta0,
                    WtT + (size_t)l * 2 * 256 * 512,
                    WkT + (size_t)l * 2 * 256 * 256, bk + l * 512, qn, hw, beta_p, xjt, att);
        if (l == 0)
            aggregate_kernel<1><<<AGB, 256, 0, stream>>>(att, xjt, ofs, h,
                    ln_g + DD, ln_b + DD, hn);
        else
            aggregate_kernel<0><<<AGB, 256, 0, stream>>>(att, xjt, ofs, h,
                    ln_g, ln_b, hn);
    }
}

// Round 19
// 1122.205 us; speedup vs baseline: 1.1930x; 1.1930x over previous
//
#include <hip/hip_runtime.h>
#include <hip/hip_bf16.h>

#define NN 50000
#define NE 300000
#define DD 256
#define NCHUNK 293   // ceil(NE/1024)

typedef __hip_bfloat16 bf16;
typedef __attribute__((ext_vector_type(8))) short bf16x8;
typedef __attribute__((ext_vector_type(4))) float f32x4;

__device__ __forceinline__ float bf2f(bf16 v) { return __bfloat162float(v); }
__device__ __forceinline__ unsigned short f2b(float v) {
    bf16 t = __float2bfloat16(v);
    return *reinterpret_cast<unsigned short*>(&t);
}
__device__ __forceinline__ float b2f_bits(unsigned short u) {
    return __uint_as_float(((unsigned)u) << 16);
}
// tanh-form gelu: max err ~1e-3, branch-free
__device__ __forceinline__ float gelu_f(float v) {
    float v2 = v * v;
    float z  = v * fmaf(v2, 0.044715f, 1.0f) * 0.7978845608f;
    float e  = __expf(2.0f * z);
    float th = 1.0f - 2.0f / (e + 1.0f);
    return 0.5f * v * (1.0f + th);
}
// async global->LDS, 16B per lane; LDS dest = base + lane*16 (wave-linear)
__device__ __forceinline__ void gl2lds16(const uint4* g, uint4* l) {
    __builtin_amdgcn_global_load_lds(
        (const __attribute__((address_space(1))) void*)g,
        (__attribute__((address_space(3))) void*)l, 16, 0, 0);
}

// ---------------- edge partition by kg (stable, deterministic) ----------------
__global__ void part_count(const int* __restrict__ kg, int* __restrict__ bcnt) {
    int base = blockIdx.x * 1024;
    __shared__ int wc[4];
    int t = threadIdx.x, wave = t >> 6, lane = t & 63;
    int cnt = 0;
    #pragma unroll
    for (int s = 0; s < 4; ++s) {
        int j = base + s * 256 + t;
        int is0 = (j < NE && kg[j] == 0) ? 1 : 0;
        unsigned long long m = __ballot(is0);
        if (lane == 0) cnt += __popcll(m);
    }
    if (lane == 0) wc[wave] = cnt;
    __syncthreads();
    if (t == 0) bcnt[blockIdx.x] = wc[0] + wc[1] + wc[2] + wc[3];
}

// parallel exclusive scan of bcnt[0..n) (n <= 512), total -> meta[0]
__global__ __launch_bounds__(512) void part_scan(const int* __restrict__ bcnt,
                                                 int* __restrict__ bofs,
                                                 int* __restrict__ meta, int n) {
    __shared__ int tmp[512];
    int t = threadIdx.x;
    int v = (t < n) ? bcnt[t] : 0;
    tmp[t] = v;
    __syncthreads();
    #pragma unroll
    for (int off = 1; off < 512; off <<= 1) {
        int u = (t >= off) ? tmp[t - off] : 0;
        __syncthreads();
        tmp[t] += u;
        __syncthreads();
    }
    if (t < n) bofs[t] = tmp[t] - v;
    if (t == n - 1) meta[0] = tmp[t];
}

__global__ void part_scatter(const int* __restrict__ kg, const int* __restrict__ bofs,
                             const int* __restrict__ meta, int* __restrict__ perm) {
    int base = blockIdx.x * 1024;
    int c0 = meta[0];
    __shared__ int wz[4];
    int t = threadIdx.x, wave = t >> 6, lane = t & 63;
    int zrun = bofs[blockIdx.x];
    for (int s = 0; s < 4; ++s) {
        int j = base + s * 256 + t;
        int valid = j < NE;
        int is0 = (valid && kg[j] == 0) ? 1 : 0;
        unsigned long long m = __ballot(is0);
        int zb = __popcll(m & ((1ull << lane) - 1ull));
        if (lane == 0) wz[wave] = __popcll(m);
        __syncthreads();
        int wbefore = 0;
        for (int w = 0; w < wave; ++w) wbefore += wz[w];
        int zeros_before = zrun + wbefore + zb;
        if (valid) {
            int pos = is0 ? zeros_before : (c0 + (j - zeros_before));
            perm[pos] = j;
        }
        int stepz = wz[0] + wz[1] + wz[2] + wz[3];
        __syncthreads();
        zrun += stepz;
    }
}

// ---------------- CSR build (dst) ----------------
__global__ void deg_hist(const int* __restrict__ dst, int* __restrict__ deg) {
    int i = blockIdx.x * blockDim.x + threadIdx.x;
    if (i < NE) atomicAdd(&deg[dst[i]], 1);
}

// parallel exclusive scan over n entries; ofs[0..n] (ofs[n]=total); cur mirrors ofs
__global__ __launch_bounds__(1024) void scan_big(const int* __restrict__ in,
                                                 int* __restrict__ ofs,
                                                 int* __restrict__ cur, int n) {
    __shared__ int part[1024];
    int t = threadIdx.x;
    int C = (n + 1023) >> 10;
    int base = t * C;
    int s = 0;
    for (int j = 0; j < C; ++j) { int idx = base + j; if (idx < n) s += in[idx]; }
    part[t] = s;
    __syncthreads();
    #pragma unroll
    for (int off = 1; off < 1024; off <<= 1) {
        int u = (t >= off) ? part[t - off] : 0;
        __syncthreads();
        part[t] += u;
        __syncthreads();
    }
    int run = (t == 0) ? 0 : part[t - 1];
    for (int j = 0; j < C; ++j) {
        int idx = base + j;
        if (idx < n) {
            ofs[idx] = run;
            if (cur) cur[idx] = run;
            run += in[idx];
        }
    }
    if (t == 1023) ofs[n] = part[1023];
}

// each edge gets its CSR slot: ipos[e]
__global__ void csr_fill_ipos(const int* __restrict__ dst, int* __restrict__ cur,
                              int* __restrict__ ipos) {
    int i = blockIdx.x * blockDim.x + threadIdx.x;
    if (i < NE) {
        int p = atomicAdd(&cur[dst[i]], 1);
        ipos[i] = p;
    }
}

// flatten perm-indexed edge attributes into coalesced arrays
__global__ void build_perm_arrays(const int* __restrict__ perm,
        const int* __restrict__ src, const int* __restrict__ dst,
        const int* __restrict__ kgd, const int* __restrict__ ipos,
        int* __restrict__ src_p, int* __restrict__ dst_p,
        int* __restrict__ kgd_p, int* __restrict__ ipos_p) {
    int i = blockIdx.x * blockDim.x + threadIdx.x;
    if (i < NE) {
        int ge = perm[i];
        src_p[i] = src[ge];
        dst_p[i] = dst[ge];
        kgd_p[i] = kgd[ge];
        ipos_p[i] = ipos[ge];
    }
}

// ---------------- prep kernels ----------------
// relb stored in PERM order: relb[pos] = bf16(rel[perm[pos]])
__global__ __launch_bounds__(256) void f2b_perm_kernel(const float* __restrict__ rel,
        const int* __restrict__ perm, ushort* __restrict__ relb) {
    int row = blockIdx.x * 4 + (threadIdx.x >> 6);
    if (row >= NE) return;
    int lane = threadIdx.x & 63;
    int ge = perm[row];
    float4 f = ((const float4*)(rel + (size_t)ge * 256))[lane];
    ushort4 o;
    o.x = f2b(f.x); o.y = f2b(f.y); o.z = f2b(f.z); o.w = f2b(f.w);
    ((ushort4*)(relb + (size_t)row * 256))[lane] = o;
}

// out[s][o][d] = bf16(in[s][d][o]), dout = 256, din = 1<<shift
__global__ void transpose_w_kernel(const float* __restrict__ in, ushort* __restrict__ out,
                                   int shift, long total) {
    long i0 = (long)blockIdx.x * blockDim.x + threadIdx.x;
    long stride = (long)gridDim.x * blockDim.x;
    long dmask = ((long)1 << shift) - 1;
    for (long i = i0; i < total; i += stride) {
        long d = i & dmask;
        long rest = i >> shift;
        long o = rest & 255;
        long s = rest >> 8;
        out[i] = f2b(in[((s << shift) + d) * 256 + o]);
    }
}

__global__ void fill_kernel(float* __restrict__ p, float v, int n) {
    for (int i = blockIdx.x * blockDim.x + threadIdx.x; i < n; i += gridDim.x * blockDim.x)
        p[i] = v;
}

// ---------------- fused cast + layer-0 layernorm: h = x; hn = LN(x) ----------------
__global__ __launch_bounds__(256) void lnx_kernel(const float* __restrict__ x,
        const float* __restrict__ g, const float* __restrict__ b,
        float* __restrict__ h, bf16* __restrict__ hn) {
    int n = blockIdx.x * 4 + (threadIdx.x >> 6);
    if (n >= NN) return;
    int t = threadIdx.x & 63;
    float4 v = ((const float4*)(x + (size_t)n * DD))[t];
    ((float4*)(h + (size_t)n * DD))[t] = v;
    float s  = v.x + v.y + v.z + v.w;
    float s2 = v.x * v.x + v.y * v.y + v.z * v.z + v.w * v.w;
    #pragma unroll
    for (int off = 32; off; off >>= 1) {
        s  += __shfl_down(s, off);
        s2 += __shfl_down(s2, off);
    }
    s = __shfl(s, 0); s2 = __shfl(s2, 0);
    float mu  = s * (1.f / DD);
    float var = s2 * (1.f / DD) - mu * mu;
    float rs  = rsqrtf(var + 1e-5f);
    float vv[4] = {v.x, v.y, v.z, v.w};
    ushort4 pk;
    unsigned short* pku = (unsigned short*)&pk;
    #pragma unroll
    for (int j = 0; j < 4; ++j) {
        int c = t * 4 + j;
        pku[j] = f2b((vv[j] - mu) * rs * g[c] + b[c]);
    }
    ((ushort4*)(hn + (size_t)n * DD))[t] = pk;
}

// ---------------- node kernel: qn[br][node] = Wq[br]@hn + bq  AND
//                  hw[br][node] = Wt_upper[br]@hn + bt (both branches, shared staging)
__global__ __launch_bounds__(512) void nodeq_mfma(
        const bf16* __restrict__ hn,
        const ushort* __restrict__ WqT, const float* __restrict__ bq,
        const ushort* __restrict__ WtT, const float* __restrict__ bt,
        ushort* __restrict__ qn, ushort* __restrict__ hw) {
    __shared__ uint4 xh[64 * 32];   // 64 rows x 512B, xor-swizzled 16B slots
    __shared__ float bqs[2][256], bts[2][256];
    int t = threadIdx.x;
    int n0 = blockIdx.x * 64;
    int wave = t >> 6, lane = t & 63;
    if (t < 256) { bqs[0][t] = bq[t]; bqs[1][t] = bq[256 + t]; }
    else { int c = t & 255; bts[0][c] = bt[c]; bts[1][c] = bt[256 + c]; }
    const uint4* hn4 = (const uint4*)hn;
    #pragma unroll
    for (int j = 0; j < 4; ++j) {
        int pr = wave * 4 + j;
        int r2 = pr * 2 + (lane >> 5);
        int node = n0 + r2; if (node >= NN) node = NN - 1;
        int s = lane & 31;
        gl2lds16(hn4 + (size_t)node * 32 + (s ^ (r2 & 7)), &xh[pr * 64]);
    }
    __syncthreads();
    int lr = lane & 15, lg = lane >> 4;
    const char* xhb = (const char*)xh;
    f32x4 acc[2][2][4];
    // ---- phase A: hw = Wt_upper @ hn + bt (both branches) ----
    #pragma unroll
    for (int b = 0; b < 2; ++b)
        #pragma unroll
        for (int m = 0; m < 2; ++m)
            #pragma unroll
            for (int n = 0; n < 4; ++n) acc[b][m][n] = (f32x4){0.f, 0.f, 0.f, 0.f};
    {
        const ushort* tr0 = WtT + (size_t)(wave * 32 + lr) * 512 + lg * 8;
        const ushort* tr1 = WtT + (size_t)(wave * 32 + 16 + lr) * 512 + lg * 8;
        #pragma unroll
        for (int kk = 0; kk < 8; ++kk) {
            bf16x8 a00 = *(const bf16x8*)(tr0 + kk * 32);
            bf16x8 a01 = *(const bf16x8*)(tr1 + kk * 32);
            bf16x8 a10 = *(const bf16x8*)(tr0 + 131072 + kk * 32);
            bf16x8 a11 = *(const bf16x8*)(tr1 + 131072 + kk * 32);
            bf16x8 bfr[4];
            #pragma unroll
            for (int n = 0; n < 4; ++n) {
                int r = n * 16 + lr;
                bfr[n] = *(const bf16x8*)(xhb + r * 512 + (((kk * 4 + lg) ^ (r & 7)) << 4));
            }
            #pragma unroll
            for (int n = 0; n < 4; ++n) {
                acc[0][0][n] = __builtin_amdgcn_mfma_f32_16x16x32_bf16(a00, bfr[n], acc[0][0][n], 0, 0, 0);
                acc[0][1][n] = __builtin_amdgcn_mfma_f32_16x16x32_bf16(a01, bfr[n], acc[0][1][n], 0, 0, 0);
                acc[1][0][n] = __builtin_amdgcn_mfma_f32_16x16x32_bf16(a10, bfr[n], acc[1][0][n], 0, 0, 0);
                acc[1][1][n] = __builtin_amdgcn_mfma_f32_16x16x32_bf16(a11, bfr[n], acc[1][1][n], 0, 0, 0);
            }
        }
    }
    #pragma unroll
    for (int n = 0; n < 4; ++n) {
        int e = n * 16 + lr;
        int node = n0 + e;
        if (node < NN) {
            #pragma unroll
            for (int br = 0; br < 2; ++br)
                #pragma unroll
                for (int m = 0; m < 2; ++m) {
                    int ob = wave * 32 + m * 16 + lg * 4;
                    f32x4 a = acc[br][m][n];
                    ushort4 pk;
                    unsigned short* pu = (unsigned short*)&pk;
                    #pragma unroll
                    for (int r = 0; r < 4; ++r) pu[r] = f2b(a[r] + bts[br][ob + r]);
                    *(ushort4*)(hw + ((size_t)br * NN + node) * 256 + ob) = pk;
                }
        }
    }
    // ---- phase B: qn = Wq @ hn + bq (both branches), reuse acc ----
    #pragma unroll
    for (int b = 0; b < 2; ++b)
        #pragma unroll
        for (int m = 0; m < 2; ++m)
            #pragma unroll
            for (int n = 0; n < 4; ++n) acc[b][m][n] = (f32x4){0.f, 0.f, 0.f, 0.f};
    {
        const ushort* qr0 = WqT + (size_t)(wave * 32 + lr) * 256 + lg * 8;
        const ushort* qr1 = WqT + (size_t)(wave * 32 + 16 + lr) * 256 + lg * 8;
        #pragma unroll
        for (int kk = 0; kk < 8; ++kk) {
            bf16x8 a00 = *(const bf16x8*)(qr0 + kk * 32);
            bf16x8 a01 = *(const bf16x8*)(qr1 + kk * 32);
            bf16x8 a10 = *(const bf16x8*)(qr0 + 65536 + kk * 32);
            bf16x8 a11 = *(const bf16x8*)(qr1 + 65536 + kk * 32);
            bf16x8 bfr[4];
            #pragma unroll
            for (int n = 0; n < 4; ++n) {
                int r = n * 16 + lr;
                bfr[n] = *(const bf16x8*)(xhb + r * 512 + (((kk * 4 + lg) ^ (r & 7)) << 4));
            }
            #pragma unroll
            for (int n = 0; n < 4; ++n) {
                acc[0][0][n] = __builtin_amdgcn_mfma_f32_16x16x32_bf16(a00, bfr[n], acc[0][0][n], 0, 0, 0);
                acc[0][1][n] = __builtin_amdgcn_mfma_f32_16x16x32_bf16(a01, bfr[n], acc[0][1][n], 0, 0, 0);
                acc[1][0][n] = __builtin_amdgcn_mfma_f32_16x16x32_bf16(a10, bfr[n], acc[1][0][n], 0, 0, 0);
                acc[1][1][n] = __builtin_amdgcn_mfma_f32_16x16x32_bf16(a11, bfr[n], acc[1][1][n], 0, 0, 0);
            }
        }
    }
    #pragma unroll
    for (int n = 0; n < 4; ++n) {
        int e = n * 16 + lr;
        int node = n0 + e;
        if (node < NN) {
            #pragma unroll
            for (int br = 0; br < 2; ++br)
                #pragma unroll
                for (int m = 0; m < 2; ++m) {
                    int ob = wave * 32 + m * 16 + lg * 4;
                    f32x4 a = acc[br][m][n];
                    ushort4 pk;
                    unsigned short* pu = (unsigned short*)&pk;
                    #pragma unroll
                    for (int r = 0; r < 4; ++r) pu[r] = f2b(a[r] + bqs[br][ob + r]);
                    *(ushort4*)(qn + ((size_t)br * NN + node) * 256 + ob) = pk;
                }
        }
    }
}

// ---------------- transfer (+fused k +fused att): kg_src-homogeneous tiles ----------------
// perm-flattened index arrays (coalesced); relb in perm order (streaming staging);
// xjt/att written to CSR slots (ipos) so aggregate reads sequentially.
template<int RELB>
__global__ __launch_bounds__(512, 4) void transfer_mfma(
        const float* __restrict__ rel, const ushort* __restrict__ relb,
        const int* __restrict__ perm,
        const int* __restrict__ src_p, const int* __restrict__ dst_p,
        const int* __restrict__ kgd_p, const int* __restrict__ ipos_p,
        const int* __restrict__ meta,
        const ushort* __restrict__ WtT,
        const ushort* __restrict__ WkT, const float* __restrict__ bk,
        const ushort* __restrict__ qn, const ushort* __restrict__ hw,
        const float* __restrict__ beta_p,
        bf16* __restrict__ xjt, float* __restrict__ att) {
    __shared__ uint4 xr[64 * 32];   // 32 KB: rel tile -> xjt tile
    __shared__ float bks[256];
    __shared__ float patt[8][64];
    __shared__ int ssrc[64], sdst[64], sgd[64], sip[64], sval[64];
    int t = threadIdx.x;
    int c0 = meta[0];
    int tiles0 = (c0 + 63) >> 6;
    int tiles1 = (NE - c0 + 63) >> 6;
    int bid = blockIdx.x;
    if (bid >= tiles0 + tiles1) return;
    int kgt, start, end;
    if (bid < tiles0) { kgt = 0; start = bid * 64; end = c0; }
    else              { kgt = 1; start = c0 + (bid - tiles0) * 64; end = NE; }
    int wave = t >> 6, lane = t & 63;
    if (t < 64) {
        int pos = start + t;
        int v = pos < end;
        int cp = v ? pos : end - 1;
        sval[t] = v;
        ssrc[t] = src_p[cp];
        sdst[t] = dst_p[cp];
        sgd[t]  = kgd_p[cp];
        sip[t]  = ipos_p[cp];
    } else if (t >= 256) {
        bks[t - 256] = bk[kgt * 256 + (t - 256)];
    }
    __syncthreads();
    // ---- stage rel tile (64 rows x 512B); perm-ordered -> address is arithmetic ----
    if (RELB) {
        const uint4* rb4 = (const uint4*)relb;
        #pragma unroll
        for (int j = 0; j < 4; ++j) {
            int pr = wave * 4 + j;
            int r2 = pr * 2 + (lane >> 5);
            int rp = start + r2; if (rp >= end) rp = end - 1;
            int s = lane & 31;
            gl2lds16(rb4 + (size_t)rp * 32 + (s ^ (r2 & 7)), &xr[pr * 64]);
        }
    } else {
        #pragma unroll
        for (int i = 0; i < 8; ++i) {
            int r = i * 8 + wave;
            int rp = start + r; if (rp >= end) rp = end - 1;
            int ge = perm[rp];
            float4 f = ((const float4*)(rel + (size_t)ge * 256))[lane];
            ushort4 o;
            o.x = f2b(f.x); o.y = f2b(f.y); o.z = f2b(f.z); o.w = f2b(f.w);
            int s = lane >> 1;
            char* bp = (char*)&xr[r * 32] + (((s ^ (r & 7)) << 4) | ((lane & 1) << 3));
            *(ushort4*)bp = o;
        }
    }
    int lr = lane & 15, lg = lane >> 4;
    // ---- gathers: hw (consumed immediately into acc) + qn (held for att) ----
    f32x4 acc[2][4];
    #pragma unroll
    for (int n = 0; n < 4; ++n) {
        int e = n * 16 + lr;
        size_t hb = ((size_t)kgt * NN + ssrc[e]) * 256;
        #pragma unroll
        for (int m = 0; m < 2; ++m) {
            int ob = wave * 32 + m * 16 + lg * 4;
            ushort4 w4 = *(const ushort4*)(hw + hb + ob);
            acc[m][n] = (f32x4){b2f_bits(w4.x), b2f_bits(w4.y), b2f_bits(w4.z), b2f_bits(w4.w)};
        }
    }
    ushort4 kv[2][4];
    #pragma unroll
    for (int n = 0; n < 4; ++n) {
        int e = n * 16 + lr;
        size_t qb = ((size_t)sgd[e] * NN + sdst[e]) * 256;
        #pragma unroll
        for (int m = 0; m < 2; ++m) {
            int ob = wave * 32 + m * 16 + lg * 4;
            kv[m][n] = *(const ushort4*)(qn + qb + ob);
        }
    }
    __syncthreads();
    // ---- 8 kk MFMA on rel with Wt_lower (acc pre-initialized from hw) ----
    const char* xrb = (const char*)xr;
    const ushort* wb = WtT + (size_t)kgt * 131072;
    const ushort* wrow0 = wb + (size_t)(wave * 32 + lr) * 512 + 256 + lg * 8;       // lower half
    const ushort* wrow1 = wb + (size_t)(wave * 32 + 16 + lr) * 512 + 256 + lg * 8;
    __builtin_amdgcn_s_setprio(1);
    #pragma unroll
    for (int kk = 0; kk < 8; ++kk) {
        bf16x8 a0 = *(const bf16x8*)(wrow0 + kk * 32);
        bf16x8 a1 = *(const bf16x8*)(wrow1 + kk * 32);
        bf16x8 bfr[4];
        #pragma unroll
        for (int n = 0; n < 4; ++n) {
            int r = n * 16 + lr;
            bfr[n] = *(const bf16x8*)(xrb + r * 512 + (((kk * 4 + lg) ^ (r & 7)) << 4));
        }
        #pragma unroll
        for (int m = 0; m < 2; ++m)
            #pragma unroll
            for (int n = 0; n < 4; ++n)
                acc[m][n] = __builtin_amdgcn_mfma_f32_16x16x32_bf16((m ? a1 : a0), bfr[n], acc[m][n], 0, 0, 0);
    }
    __builtin_amdgcn_s_setprio(0);
    __syncthreads();
    // ---- epilogue: gelu (bias already in hw), pack bf16 into swizzled 512B rows ----
    char* xob = (char*)xr;
    #pragma unroll
    for (int n = 0; n < 4; ++n) {
        int e = n * 16 + lr;
        #pragma unroll
        for (int m = 0; m < 2; ++m) {
            int ob = wave * 32 + m * 16 + lg * 4;
            f32x4 a = acc[m][n];
            ushort4 pk;
            unsigned short* pu = (unsigned short*)&pk;
            #pragma unroll
            for (int r = 0; r < 4; ++r)
                pu[r] = f2b(gelu_f(a[r]));
            int bofs = ob * 2;
            int slot = ((bofs >> 4) ^ (e & 7));
            *(ushort4*)(xob + e * 512 + slot * 16 + (bofs & 15)) = pk;
        }
    }
    __syncthreads();
    // ---- xjt global store to CSR slots (drains under the k-pass MFMA) ----
    uint4* xjv = (uint4*)xjt;
    #pragma unroll
    for (int i = 0; i < 4; ++i) {
        int flat = i * 512 + t;
        int r = flat >> 5, c = flat & 31;
        if (sval[r])
            xjv[(size_t)sip[r] * 32 + c] = *(const uint4*)(xob + r * 512 + ((c ^ (r & 7)) << 4));
    }
    // ---- fused k-pass: k = Wk[kg] @ xjt_tile (reuses acc) ----
    #pragma unroll
    for (int m = 0; m < 2; ++m)
        #pragma unroll
        for (int n = 0; n < 4; ++n) acc[m][n] = (f32x4){0.f, 0.f, 0.f, 0.f};
    const ushort* kbw = WkT + (size_t)kgt * 65536;
    const ushort* kr0 = kbw + (size_t)(wave * 32 + lr) * 256 + lg * 8;
    const ushort* kr1 = kbw + (size_t)(wave * 32 + 16 + lr) * 256 + lg * 8;
    __builtin_amdgcn_s_setprio(1);
    #pragma unroll
    for (int kk = 0; kk < 8; ++kk) {
        bf16x8 a0 = *(const bf16x8*)(kr0 + kk * 32);
        bf16x8 a1 = *(const bf16x8*)(kr1 + kk * 32);
        bf16x8 bfr[4];
        #pragma unroll
        for (int n = 0; n < 4; ++n) {
            int r = n * 16 + lr;
            bfr[n] = *(const bf16x8*)(xob + r * 512 + (((kk * 4 + lg) ^ (r & 7)) << 4));
        }
        #pragma unroll
        for (int n = 0; n < 4; ++n) {
            acc[0][n] = __builtin_amdgcn_mfma_f32_16x16x32_bf16(a0, bfr[n], acc[0][n], 0, 0, 0);
            acc[1][n] = __builtin_amdgcn_mfma_f32_16x16x32_bf16(a1, bfr[n], acc[1][n], 0, 0, 0);
        }
    }
    __builtin_amdgcn_s_setprio(0);
    // ---- fused att: lane-local q.k dot with pre-gathered kv, reduce over lg ----
    float p[4];
    #pragma unroll
    for (int n = 0; n < 4; ++n) {
        float s = 0.f;
        #pragma unroll
        for (int m = 0; m < 2; ++m) {
            int ob = wave * 32 + m * 16 + lg * 4;
            ushort4 qv = kv[m][n];
            f32x4 kcv = acc[m][n];
            s = fmaf(b2f_bits(qv.x), kcv[0] + bks[ob + 0], s);
            s = fmaf(b2f_bits(qv.y), kcv[1] + bks[ob + 1], s);
            s = fmaf(b2f_bits(qv.z), kcv[2] + bks[ob + 2], s);
            s = fmaf(b2f_bits(qv.w), kcv[3] + bks[ob + 3], s);
        }
        p[n] = s;
    }
    #pragma unroll
    for (int n = 0; n < 4; ++n) {
        p[n] += __shfl_xor(p[n], 16);
        p[n] += __shfl_xor(p[n], 32);
    }
    if (lane < 16) {
        #pragma unroll
        for (int n = 0; n < 4; ++n) patt[wave][n * 16 + lr] = p[n];
    }
    __syncthreads();
    if (t < 256) {
        int e = t & 63, h = t >> 6;
        if (sval[e]) {
            int pos = start + e;
            float bv = beta_p[pos];
            att[(size_t)sip[e] * 4 + h] = (patt[2 * h][e] + patt[2 * h + 1][e]) * bv * 0.125f;
        }
    }
}

// ---------------- fused softmax + aggregate + residual + gelu (+ next-layer LN) ----------------
// att/xjt are in CSR-slot order -> fully sequential reads, no eid indirection
template<int WRITE_HN>
__global__ __launch_bounds__(256) void aggregate_kernel(
        const float* __restrict__ att, const bf16* __restrict__ xjt,
        const int* __restrict__ ofs,
        float* __restrict__ h, const float* __restrict__ g, const float* __restrict__ b,
        bf16* __restrict__ hn) {
    int node = blockIdx.x * 4 + (threadIdx.x >> 6);
    if (node >= NN) return;
    int lane = threadIdx.x & 63;
    int hh = lane >> 4;
    int beg = ofs[node], end = ofs[node + 1];
    float m = -1e30f, den = 0.f;
    float a0 = 0.f, a1 = 0.f, a2 = 0.f, a3 = 0.f;
    for (int i = beg; i < end; ++i) {
        float av = att[(size_t)i * 4 + hh];
        if (av > m) {
            float r = __expf(m - av);
            den *= r; a0 *= r; a1 *= r; a2 *= r; a3 *= r;
            m = av;
        }
        float wgt = __expf(av - m);
        den += wgt;
        ushort4 v = *(const ushort4*)((const ushort*)xjt + (size_t)i * 256 + lane * 4);
        a0 = fmaf(wgt, b2f_bits(v.x), a0);
        a1 = fmaf(wgt, b2f_bits(v.y), a1);
        a2 = fmaf(wgt, b2f_bits(v.z), a2);
        a3 = fmaf(wgt, b2f_bits(v.w), a3);
    }
    float inv = 1.f / (den + 1e-16f);
    float4 hv = ((float4*)(h + (size_t)node * 256))[lane];
    hv.x += gelu_f(a0 * inv);
    hv.y += gelu_f(a1 * inv);
    hv.z += gelu_f(a2 * inv);
    hv.w += gelu_f(a3 * inv);
    ((float4*)(h + (size_t)node * 256))[lane] = hv;
    if (WRITE_HN) {
        float s  = hv.x + hv.y + hv.z + hv.w;
        float s2 = hv.x * hv.x + hv.y * hv.y + hv.z * hv.z + hv.w * hv.w;
        #pragma unroll
        for (int off = 32; off; off >>= 1) {
            s  += __shfl_down(s, off);
            s2 += __shfl_down(s2, off);
        }
        s = __shfl(s, 0); s2 = __shfl(s2, 0);
        float mu  = s * (1.f / DD);
        float var = s2 * (1.f / DD) - mu * mu;
        float rs  = rsqrtf(var + 1e-5f);
        float vv[4] = {hv.x, hv.y, hv.z, hv.w};
        ushort4 pk;
        unsigned short* pku = (unsigned short*)&pk;
        #pragma unroll
        for (int j = 0; j < 4; ++j) {
            int c = lane * 4 + j;
            pku[j] = f2b((vv[j] - mu) * rs * g[c] + b[c]);
        }
        ((ushort4*)(hn + (size_t)node * DD))[lane] = pk;
    }
}

// beta in perm order (coalesced read in transfer's att write)
__global__ void beta_perm_kernel(const float* __restrict__ beta, const int* __restrict__ perm,
                                 float* __restrict__ beta_p) {
    int i = blockIdx.x * blockDim.x + threadIdx.x;
    if (i < NE) beta_p[i] = beta[perm[i]];
}

extern "C" void kernel_launch(void* const* d_in, const int* in_sizes, int n_in,
                              void* d_out, int out_size, void* d_ws, size_t ws_size,
                              hipStream_t stream) {
    const float* x    = (const float*)d_in[0];
    const int*   ei   = (const int*)d_in[1];
    const int*   ekg  = (const int*)d_in[2];
    const float* beta = (const float*)d_in[3];
    const float* rel  = (const float*)d_in[4];
    const float* ln_g = (const float*)d_in[5];
    const float* ln_b = (const float*)d_in[6];
    const float* Wt   = (const float*)d_in[7];
    const float* bt   = (const float*)d_in[8];
    const float* Wq   = (const float*)d_in[9];
    const float* bq   = (const float*)d_in[10];
    const float* Wk   = (const float*)d_in[11];
    const float* bk   = (const float*)d_in[12];

    float* h = (float*)d_out;   // residual stream (f32) in d_out

    const int* srcp = ei;
    const int* dstp = ei + NE;
    const int* kgs  = ekg;
    const int* kgd  = ekg + NE;

    char* w = (char*)d_ws;
    float*  att   = (float*)w;  w += (size_t)NE * 4 * 4;         //  4.8 MB
    bf16*   hn    = (bf16*)w;   w += (size_t)NN * DD * 2;        // 25.6 MB
    bf16*   xjt   = (bf16*)w;   w += (size_t)NE * DD * 2;        // 153.6 MB
    ushort* qn    = (ushort*)w; w += (size_t)2 * NN * DD * 2;    // 51.2 MB
    ushort* hw    = (ushort*)w; w += (size_t)2 * NN * DD * 2;    // 51.2 MB
    ushort* WtT   = (ushort*)w; w += (size_t)4 * 256 * 512 * 2;  // 1 MB
    ushort* WqT   = (ushort*)w; w += (size_t)4 * 256 * 256 * 2;
    ushort* WkT   = (ushort*)w; w += (size_t)4 * 256 * 256 * 2;
    int* perm_src = (int*)w;    w += (size_t)NE * 4;             // 1.2 MB
    int* bcnt0    = (int*)w;    w += NCHUNK * 4;
    int* bofs0    = (int*)w;    w += NCHUNK * 4;
    int* meta0    = (int*)w;    w += 64;
    int* deg      = (int*)w;    w += (size_t)NN * 4;
    int* ofs      = (int*)w;    w += (size_t)(NN + 1) * 4;
    int* cur      = (int*)w;    w += (size_t)NN * 4;
    int* ipos     = (int*)w;    w += (size_t)NE * 4;             // 1.2 MB
    int* src_p    = (int*)w;    w += (size_t)NE * 4;
    int* dst_p    = (int*)w;    w += (size_t)NE * 4;
    int* kgd_p    = (int*)w;    w += (size_t)NE * 4;
    int* ipos_p   = (int*)w;    w += (size_t)NE * 4;
    float* beta_p = (float*)w;  w += (size_t)NE * 4;
    size_t used = (size_t)(w - (char*)d_ws);
    ushort* relb = (ushort*)w;
    int use_relb = (ws_size >= used + (size_t)NE * DD * 2) ? 1 : 0;

    // edge partition by kg_src (stable, static across layers)
    part_count<<<NCHUNK, 256, 0, stream>>>(kgs, bcnt0);
    part_scan<<<1, 512, 0, stream>>>(bcnt0, bofs0, meta0, NCHUNK);
    part_scatter<<<NCHUNK, 256, 0, stream>>>(kgs, bofs0, meta0, perm_src);

    // CSR slots by dst
    fill_kernel<<<64, 256, 0, stream>>>((float*)deg, 0.f, NN);
    deg_hist<<<(NE + 255) / 256, 256, 0, stream>>>(dstp, deg);
    scan_big<<<1, 1024, 0, stream>>>(deg, ofs, cur, NN);
    csr_fill_ipos<<<(NE + 255) / 256, 256, 0, stream>>>(dstp, cur, ipos);

    // perm-flattened edge attribute arrays
    build_perm_arrays<<<(NE + 255) / 256, 256, 0, stream>>>(perm_src, srcp, dstp, kgd, ipos,
            src_p, dst_p, kgd_p, ipos_p);
    beta_perm_kernel<<<(NE + 255) / 256, 256, 0, stream>>>(beta, perm_src, beta_p);

    if (use_relb)
        f2b_perm_kernel<<<(NE + 3) / 4, 256, 0, stream>>>(rel, perm_src, relb);
    transpose_w_kernel<<<512, 256, 0, stream>>>(Wt, WtT, 9, (long)4 * 256 * 512);
    transpose_w_kernel<<<256, 256, 0, stream>>>(Wq, WqT, 8, (long)4 * 256 * 256);
    transpose_w_kernel<<<256, 256, 0, stream>>>(Wk, WkT, 8, (long)4 * 256 * 256);

    const int EBP = (NE + 126) / 64;   // max tiles over both kg halves
    const int QB  = (NN + 63) / 64;
    const int AGB = (NN + 3) / 4;

    // layer 0: fused cast + LN
    lnx_kernel<<<AGB, 256, 0, stream>>>(x, ln_g, ln_b, h, hn);
    for (int l = 0; l < 2; ++l) {
        nodeq_mfma<<<QB, 512, 0, stream>>>(hn,
                WqT + (size_t)l * 2 * 256 * 256, bq + l * 512,
                WtT + (size_t)l * 2 * 256 * 512, bt + l * 512, qn, hw);
        if (use_relb)
            transfer_mfma<1><<<EBP, 512, 0, stream>>>(rel, relb, perm_src,
                    src_p, dst_p, kgd_p, ipos_p, meta0,
                    WtT + (size_t)l * 2 * 256 * 512,
                    WkT + (size_t)l * 2 * 256 * 256, bk + l * 512, qn, hw, beta_p, xjt, att);
        else
            transfer_mfma<0><<<EBP, 512, 0, stream>>>(rel, relb, perm_src,
                    src_p, dst_p, kgd_p, ipos_p, meta0,
                    WtT + (size_t)l * 2 * 256 * 512,
                    WkT + (size_t)l * 2 * 256 * 256, bk + l * 512, qn, hw, beta_p, xjt, att);
        if (l == 0)
            aggregate_kernel<1><<<AGB, 256, 0, stream>>>(att, xjt, ofs, h,
                    ln_g + DD, ln_b + DD, hn);
        else
            aggregate_kernel<0><<<AGB, 256, 0, stream>>>(att, xjt, ofs, h,
                    ln_g, ln_b, hn);
    }
}